// Round 10
// baseline (129.167 us; speedup 1.0000x reference)
//
#include <hip/hip_runtime.h>
#include <hip/hip_bf16.h>

#define B_SZ 256
#define L_SZ 50
#define N_SZ 100000
#define D_SZ 128
#define NBT ((N_SZ + 63) / 64)   // 1563 col-tiles of 64
#define GRID_G 512               // k_gemm blocks; block b walks tiles b, b+512, ...

typedef __attribute__((ext_vector_type(8))) short bf16x8;
typedef __attribute__((ext_vector_type(4))) float f32x4;

__device__ inline unsigned short f2bf(float f) {
    union { float f; unsigned u; } v; v.f = f;
    unsigned r = v.u + 0x7FFFu + ((v.u >> 16) & 1u);   // round-to-nearest-even
    return (unsigned short)(r >> 16);
}

// ---------------- kernel 1: per-b, gather v, qW1/qW2, att, u -> bf16 (512 thr, fused prep)
__global__ __launch_bounds__(512) void k_ub(const int* __restrict__ seeds,
                                            const float* __restrict__ E,
                                            const float* __restrict__ pe,
                                            const float* __restrict__ W1,
                                            const float* __restrict__ W2,
                                            const float* __restrict__ q,
                                            const float* __restrict__ b_att,
                                            unsigned short* __restrict__ u_bf,
                                            float* __restrict__ loss_slot) {
    __shared__ float vbuf[L_SZ][D_SZ + 1];
    __shared__ int   sseed[L_SZ];
    __shared__ float qs[D_SZ], qw1s[D_SZ], qw2s[D_SZ];
    __shared__ float part1[4][D_SZ], part2[4][D_SZ];
    __shared__ float att[L_SZ];
    __shared__ float c2s, qsums;
    int b = blockIdx.x, t = threadIdx.x;
    int g = t >> 7, d = t & 127;             // 4 groups x 128 threads

    if (t < L_SZ) sseed[t] = seeds[b * L_SZ + t];
    if (t < D_SZ) qs[t] = q[t];
    __syncthreads();

    // gather: group g handles rows l = g, g+4, ... (independent -> ILP)
    #pragma unroll 4
    for (int l = g; l < L_SZ; l += 4)
        vbuf[l][d] = E[(size_t)sseed[l] * D_SZ + d] + pe[l * D_SZ + d];

    // qW1/qW2: group g sums e in [g*32, g*32+32)
    {
        float a1 = 0.f, a2 = 0.f;
        int e0 = g * 32;
        #pragma unroll 8
        for (int e = e0; e < e0 + 32; ++e) {
            float qe = qs[e];
            a1 += qe * W1[e * D_SZ + d];
            a2 += qe * W2[e * D_SZ + d];
        }
        part1[g][d] = a1;
        part2[g][d] = a2;
    }
    __syncthreads();
    if (t < D_SZ) {
        qw1s[t] = part1[0][t] + part1[1][t] + part1[2][t] + part1[3][t];
        qw2s[t] = part2[0][t] + part2[1][t] + part2[2][t] + part2[3][t];
    }
    __syncthreads();

    // att[l] = vbuf[l,:] . qw1  — 8 lanes per row, shuffle-reduce (width 8)
    if (t < L_SZ * 8) {
        int l = t >> 3, sub = t & 7;
        float p = 0.f;
        #pragma unroll
        for (int k = sub * 16; k < sub * 16 + 16; ++k) p += vbuf[l][k] * qw1s[k];
        p += __shfl_xor(p, 1, 8);
        p += __shfl_xor(p, 2, 8);
        p += __shfl_xor(p, 4, 8);
        if (sub == 0) att[l] = p;
    } else if (t < L_SZ * 8 + 8) {           // c2 = vn . qw2
        int sub = t & 7;
        float p = 0.f;
        #pragma unroll
        for (int k = sub * 16; k < sub * 16 + 16; ++k) p += vbuf[L_SZ - 1][k] * qw2s[k];
        p += __shfl_xor(p, 1, 8);
        p += __shfl_xor(p, 2, 8);
        p += __shfl_xor(p, 4, 8);
        if (sub == 0) c2s = p;
    } else if (t < L_SZ * 8 + 16) {          // qsum
        int sub = t & 7;
        float p = 0.f;
        #pragma unroll
        for (int k = sub * 16; k < sub * 16 + 16; ++k) p += qs[k];
        p += __shfl_xor(p, 1, 8);
        p += __shfl_xor(p, 2, 8);
        p += __shfl_xor(p, 4, 8);
        if (sub == 0) qsums = p;
    }
    __syncthreads();

    // u[d] = sum_l (att[l]+add) * vbuf[l][d], l split over 4 groups
    float add = c2s + b_att[0] * qsums;
    float up = 0.f;
    #pragma unroll 4
    for (int l = g; l < L_SZ; l += 4) up += (att[l] + add) * vbuf[l][d];
    __syncthreads();                          // part1 free for reuse
    part1[g][d] = up;
    __syncthreads();
    if (t < D_SZ)
        u_bf[b * D_SZ + t] = f2bf(part1[0][t] + part1[1][t] + part1[2][t] + part1[3][t]);

    if (b == 0 && t == 0) loss_slot[0] = 0.f;
}

// ---------------- kernel 2: scores = u @ E^T + bias (bf16 MFMA, multi-tile amortized)
// 512 blocks (2/CU), 512 thr = 8 waves. Full u (64 KB) staged+swizzled ONCE per
// block; block walks tiles ct = bid, bid+512, ... (~3 tiles). Stores recur each
// tile -> write stream stays busy; next tile's E-frags prefetch during current
// MFMAs. E still read exactly once chip-wide; 64-col tiles fully cover lines.
// Wave w: col-panel (w&3)*16 within tile, rs-half w>>2. Per-row expsums
// accumulate in lds_sum across tiles; partial indexed by bid.
__global__ __launch_bounds__(512, 4) void k_gemm(const float* __restrict__ E,
                                                 const float* __restrict__ out_bias,
                                                 const unsigned short* __restrict__ u_bf,
                                                 float* __restrict__ scores,
                                                 float* __restrict__ partial) {
    __shared__ unsigned short us[B_SZ * D_SZ];   // 64 KB swizzled u
    __shared__ float lds_sum[B_SZ];
    int tid = threadIdx.x;
    int w = tid >> 6, lane = tid & 63;
    int wc = w & 3, rsh = w >> 2;
    if (tid < B_SZ) lds_sum[tid] = 0.f;

    // ---- stage u once: coalesced 16B/thread global reads, swizzled LDS writes
    #pragma unroll
    for (int r = 0; r < 8; ++r) {
        int off = r * 8192 + tid * 16;           // flat byte offset into u_bf
        int brow = off >> 8, inrow = off & 255;
        bf16x8 v = *(const bf16x8*)((const char*)u_bf + off);
        *(bf16x8*)((char*)us + brow * 256 + (inrow ^ ((brow & 7) << 4))) = v;
    }

    int lo = lane & 15, hi = lane >> 4;
    int kb = hi * 8;

    // E-frag loader for tile ct: rows nc+lo, f32 -> bf16
    auto loadE = [&](int ct, bf16x8* f4) {
        int nc = ct * 64 + wc * 16;
        long erow = (nc < N_SZ) ? (nc + lo) : 0;
        #pragma unroll
        for (int ks = 0; ks < 4; ++ks) {
            const float* p = E + (size_t)erow * D_SZ + ks * 32 + kb;
            float4 x = *(const float4*)p;
            float4 y = *(const float4*)(p + 4);
            bf16x8 f;
            f[0] = (short)f2bf(x.x); f[1] = (short)f2bf(x.y);
            f[2] = (short)f2bf(x.z); f[3] = (short)f2bf(x.w);
            f[4] = (short)f2bf(y.x); f[5] = (short)f2bf(y.y);
            f[6] = (short)f2bf(y.z); f[7] = (short)f2bf(y.w);
            f4[ks] = f;
        }
    };

    bf16x8 efrag[4];
    loadE(blockIdx.x, efrag);
    __syncthreads();                             // u staged; lds_sum zeroed

    for (int ct = blockIdx.x; ct < NBT; ct += GRID_G) {
        int ctn = ct + GRID_G;
        bf16x8 nfrag[4];
        loadE(ctn < NBT ? ctn : ct, nfrag);      // prefetch next tile (overlaps MFMAs)

        int nc = ct * 64 + wc * 16;
        bool valid = (nc < N_SZ);                // wave-uniform (N_SZ % 16 == 0)
        int nb = valid ? (nc + hi * 4) : 0;      // this lane's 4 consecutive n
        float4 bias4 = *(const float4*)(out_bias + nb);

        f32x4 acc[8];
        #pragma unroll
        for (int i = 0; i < 8; ++i) acc[i] = (f32x4){0.f, 0.f, 0.f, 0.f};

        #pragma unroll
        for (int ks = 0; ks < 4; ++ks) {
            int kcol = ks * 64 + hi * 16;        // byte offset of 16B k-chunk
            #pragma unroll
            for (int r8 = 0; r8 < 8; ++r8) {
                int brow = (rsh * 8 + r8) * 16 + lo;
                bf16x8 uf = *(const bf16x8*)((const char*)us + brow * 256 + (kcol ^ ((brow & 7) << 4)));
                acc[r8] = __builtin_amdgcn_mfma_f32_16x16x32_bf16(efrag[ks], uf, acc[r8], 0, 0, 0);
            }
        }

        #pragma unroll
        for (int r8 = 0; r8 < 8; ++r8) {
            int jr = (rsh * 8 + r8) * 16 + lo;   // this lane's b-row
            f32x4 c;
            c[0] = acc[r8][0] + bias4.x;
            c[1] = acc[r8][1] + bias4.y;
            c[2] = acc[r8][2] + bias4.z;
            c[3] = acc[r8][3] + bias4.w;
            if (valid)
                *(f32x4*)(scores + (size_t)jr * N_SZ + nb) = c;
            float p = __expf(c[0]) + __expf(c[1]) + __expf(c[2]) + __expf(c[3]);
            p += __shfl_xor(p, 16);
            p += __shfl_xor(p, 32);              // lanes {l, l^16, l^32, l^48} share jr
            if (valid && hi == 0) atomicAdd(&lds_sum[jr], p);
        }

        efrag[0] = nfrag[0]; efrag[1] = nfrag[1];
        efrag[2] = nfrag[2]; efrag[3] = nfrag[3];
    }
    __syncthreads();
    if (tid < B_SZ) partial[(size_t)blockIdx.x * B_SZ + tid] = lds_sum[tid];
}

// ---------------- kernel 3: per-row logsumexp + NLL mean
__global__ __launch_bounds__(256) void k_loss(const float* __restrict__ partial,
                                              const float* __restrict__ scores,
                                              const int* __restrict__ labels,
                                              float* __restrict__ out_loss) {
    int b = blockIdx.x, t = threadIdx.x;
    float acc = 0.f;
    for (int i = t; i < GRID_G; i += 256) acc += partial[(size_t)i * B_SZ + b];
    __shared__ float red[256];
    red[t] = acc;
    __syncthreads();
    for (int s = 128; s > 0; s >>= 1) {
        if (t < s) red[t] += red[t + s];
        __syncthreads();
    }
    if (t == 0) {
        int lab = labels[b];
        float val = scores[(size_t)b * N_SZ + lab] - logf(red[0]);
        atomicAdd(out_loss, -val * (1.0f / (float)B_SZ));
    }
}

extern "C" void kernel_launch(void* const* d_in, const int* in_sizes, int n_in,
                              void* d_out, int out_size, void* d_ws, size_t ws_size,
                              hipStream_t stream) {
    const int*   seeds    = (const int*)d_in[0];
    const int*   labels   = (const int*)d_in[1];
    const float* E        = (const float*)d_in[2];
    const float* W1       = (const float*)d_in[3];
    const float* W2       = (const float*)d_in[4];
    const float* q        = (const float*)d_in[5];
    const float* b_att    = (const float*)d_in[6];
    const float* out_bias = (const float*)d_in[7];
    const float* pe       = (const float*)d_in[8];

    float* scores = (float*)d_out;
    float* loss   = scores + (size_t)B_SZ * N_SZ;

    // ws layout: @2048 u_bf16 (64KB) | @67584 partial (512*256*4 = 512KB)
    unsigned short* u_bf    = (unsigned short*)((char*)d_ws + 2048);
    float*          partial = (float*)((char*)d_ws + 67584);

    k_ub<<<B_SZ, 512, 0, stream>>>(seeds, E, pe, W1, W2, q, b_att, u_bf, loss);
    k_gemm<<<GRID_G, 512, 0, stream>>>(E, out_bias, u_bf, scores, partial);
    k_loss<<<B_SZ, 256, 0, stream>>>(partial, scores, labels, loss);
}

// Round 11
// 102.279 us; speedup vs baseline: 1.2629x; 1.2629x over previous
//
#include <hip/hip_runtime.h>
#include <hip/hip_bf16.h>

#define B_SZ 256
#define L_SZ 50
#define N_SZ 100000
#define D_SZ 128
#define NBT ((N_SZ + 63) / 64)   // 1563 col-tiles of 64

typedef __attribute__((ext_vector_type(8))) short bf16x8;
typedef __attribute__((ext_vector_type(4))) float f32x4;

__device__ inline unsigned short f2bf(float f) {
    union { float f; unsigned u; } v; v.f = f;
    unsigned r = v.u + 0x7FFFu + ((v.u >> 16) & 1u);   // round-to-nearest-even
    return (unsigned short)(r >> 16);
}

// ---------------- kernel 1: per-b, gather v, qW1/qW2, att, u -> bf16 frags (512 thr)
// Output u in MFMA FRAGMENT ORDER: for b-row b (rs=b>>4, lo=b&15) and dim d
// (ks=d>>5, hi=(d>>3)&3, j=d&7): u_fr[((ks*16+rs)*64 + hi*16+lo)*8 + j].
// k_gemm then loads B-operands as coalesced lane-indexed 16B reads — no LDS stage.
__global__ __launch_bounds__(512) void k_ub(const int* __restrict__ seeds,
                                            const float* __restrict__ E,
                                            const float* __restrict__ pe,
                                            const float* __restrict__ W1,
                                            const float* __restrict__ W2,
                                            const float* __restrict__ q,
                                            const float* __restrict__ b_att,
                                            unsigned short* __restrict__ u_fr,
                                            float* __restrict__ loss_slot) {
    __shared__ float vbuf[L_SZ][D_SZ + 1];
    __shared__ int   sseed[L_SZ];
    __shared__ float qs[D_SZ], qw1s[D_SZ], qw2s[D_SZ];
    __shared__ float part1[4][D_SZ], part2[4][D_SZ];
    __shared__ float att[L_SZ];
    __shared__ float c2s, qsums;
    int b = blockIdx.x, t = threadIdx.x;
    int g = t >> 7, d = t & 127;             // 4 groups x 128 threads

    if (t < L_SZ) sseed[t] = seeds[b * L_SZ + t];
    if (t < D_SZ) qs[t] = q[t];
    __syncthreads();

    // gather: group g handles rows l = g, g+4, ... (independent -> ILP)
    #pragma unroll 4
    for (int l = g; l < L_SZ; l += 4)
        vbuf[l][d] = E[(size_t)sseed[l] * D_SZ + d] + pe[l * D_SZ + d];

    // qW1/qW2: group g sums e in [g*32, g*32+32)
    {
        float a1 = 0.f, a2 = 0.f;
        int e0 = g * 32;
        #pragma unroll 8
        for (int e = e0; e < e0 + 32; ++e) {
            float qe = qs[e];
            a1 += qe * W1[e * D_SZ + d];
            a2 += qe * W2[e * D_SZ + d];
        }
        part1[g][d] = a1;
        part2[g][d] = a2;
    }
    __syncthreads();
    if (t < D_SZ) {
        qw1s[t] = part1[0][t] + part1[1][t] + part1[2][t] + part1[3][t];
        qw2s[t] = part2[0][t] + part2[1][t] + part2[2][t] + part2[3][t];
    }
    __syncthreads();

    // att[l] = vbuf[l,:] . qw1  — 8 lanes per row, shuffle-reduce (width 8)
    if (t < L_SZ * 8) {
        int l = t >> 3, sub = t & 7;
        float p = 0.f;
        #pragma unroll
        for (int k = sub * 16; k < sub * 16 + 16; ++k) p += vbuf[l][k] * qw1s[k];
        p += __shfl_xor(p, 1, 8);
        p += __shfl_xor(p, 2, 8);
        p += __shfl_xor(p, 4, 8);
        if (sub == 0) att[l] = p;
    } else if (t < L_SZ * 8 + 8) {           // c2 = vn . qw2
        int sub = t & 7;
        float p = 0.f;
        #pragma unroll
        for (int k = sub * 16; k < sub * 16 + 16; ++k) p += vbuf[L_SZ - 1][k] * qw2s[k];
        p += __shfl_xor(p, 1, 8);
        p += __shfl_xor(p, 2, 8);
        p += __shfl_xor(p, 4, 8);
        if (sub == 0) c2s = p;
    } else if (t < L_SZ * 8 + 16) {          // qsum
        int sub = t & 7;
        float p = 0.f;
        #pragma unroll
        for (int k = sub * 16; k < sub * 16 + 16; ++k) p += qs[k];
        p += __shfl_xor(p, 1, 8);
        p += __shfl_xor(p, 2, 8);
        p += __shfl_xor(p, 4, 8);
        if (sub == 0) qsums = p;
    }
    __syncthreads();

    // u[d] = sum_l (att[l]+add) * vbuf[l][d], l split over 4 groups
    float add = c2s + b_att[0] * qsums;
    float up = 0.f;
    #pragma unroll 4
    for (int l = g; l < L_SZ; l += 4) up += (att[l] + add) * vbuf[l][d];
    __syncthreads();                          // part1 free for reuse
    part1[g][d] = up;
    __syncthreads();
    if (t < D_SZ) {
        float uval = part1[0][t] + part1[1][t] + part1[2][t] + part1[3][t];
        int rs = b >> 4, lo = b & 15;
        int ks = t >> 5, hi = (t >> 3) & 3, j = t & 7;
        u_fr[(size_t)((ks * 16 + rs) * 64 + hi * 16 + lo) * 8 + j] = f2bf(uval);
    }

    if (b == 0 && t == 0) loss_slot[0] = 0.f;
}

// ---------------- kernel 2: scores = u @ E^T + bias (bf16 MFMA, register-B)
// 1563 blocks (1:1 with 64-col tiles, dispatch order) x 256 thr = 4 waves
// (wave = 16-col panel). NO u LDS stage: B-frags are coalesced 16B loads from
// the 64 KB fragment-ordered u_fr (L2-resident). LDS = 1 KB -> up to 8 blk/CU,
// TLP hides store/load latency. rs grouped by 4 to keep VGPR <= 128.
// D layout: row=(lane>>4)*4+g -> n, col=lane&15 -> b => 16B stores per lane.
__global__ __launch_bounds__(256, 4) void k_gemm(const float* __restrict__ E,
                                                 const float* __restrict__ out_bias,
                                                 const unsigned short* __restrict__ u_fr,
                                                 float* __restrict__ scores,
                                                 float* __restrict__ partial) {
    __shared__ float lds_sum[B_SZ];
    int tid = threadIdx.x;
    int w = tid >> 6, lane = tid & 63;
    lds_sum[tid] = 0.f;

    int nc = blockIdx.x * 64 + w * 16;           // this wave's 16-col panel
    bool valid = (nc < N_SZ);                    // wave-uniform (N_SZ % 16 == 0)
    int lo = lane & 15, hi = lane >> 4;
    int kb = hi * 8;

    // ---- A fragments: E rows (= score cols), f32 -> bf16 in regs
    long erow = valid ? (nc + lo) : 0;
    bf16x8 efrag[4];
    #pragma unroll
    for (int ks = 0; ks < 4; ++ks) {
        const float* p = E + (size_t)erow * D_SZ + ks * 32 + kb;
        float4 x = *(const float4*)p;
        float4 y = *(const float4*)(p + 4);
        bf16x8 f;
        f[0] = (short)f2bf(x.x); f[1] = (short)f2bf(x.y);
        f[2] = (short)f2bf(x.z); f[3] = (short)f2bf(x.w);
        f[4] = (short)f2bf(y.x); f[5] = (short)f2bf(y.y);
        f[6] = (short)f2bf(y.z); f[7] = (short)f2bf(y.w);
        efrag[ks] = f;
    }
    int nb = valid ? (nc + hi * 4) : 0;          // this lane's 4 consecutive n
    float4 bias4 = *(const float4*)(out_bias + nb);

    __syncthreads();                             // lds_sum zeroed

    // ---- 4 groups of 4 rs: load 16 B-frags (coalesced), 16 MFMAs, epilogue
    #pragma unroll
    for (int grp = 0; grp < 4; ++grp) {
        bf16x8 bfr[4][4];                        // [ks][r4]
        #pragma unroll
        for (int ks = 0; ks < 4; ++ks)
            #pragma unroll
            for (int r4 = 0; r4 < 4; ++r4)
                bfr[ks][r4] = *(const bf16x8*)(u_fr + (size_t)((ks * 16 + grp * 4 + r4) * 64 + lane) * 8);

        f32x4 acc[4];
        #pragma unroll
        for (int i = 0; i < 4; ++i) acc[i] = (f32x4){0.f, 0.f, 0.f, 0.f};
        #pragma unroll
        for (int ks = 0; ks < 4; ++ks)
            #pragma unroll
            for (int r4 = 0; r4 < 4; ++r4)
                acc[r4] = __builtin_amdgcn_mfma_f32_16x16x32_bf16(efrag[ks], bfr[ks][r4], acc[r4], 0, 0, 0);

        #pragma unroll
        for (int r4 = 0; r4 < 4; ++r4) {
            int jr = (grp * 4 + r4) * 16 + lo;   // this lane's b-row
            f32x4 c;
            c[0] = acc[r4][0] + bias4.x;
            c[1] = acc[r4][1] + bias4.y;
            c[2] = acc[r4][2] + bias4.z;
            c[3] = acc[r4][3] + bias4.w;
            if (valid)
                *(f32x4*)(scores + (size_t)jr * N_SZ + nb) = c;
            float p = __expf(c[0]) + __expf(c[1]) + __expf(c[2]) + __expf(c[3]);
            p += __shfl_xor(p, 16);
            p += __shfl_xor(p, 32);              // lanes {l, l^16, l^32, l^48} share jr
            if (valid && hi == 0) atomicAdd(&lds_sum[jr], p);
        }
    }
    __syncthreads();
    partial[(size_t)blockIdx.x * B_SZ + tid] = lds_sum[tid];
}

// ---------------- kernel 3: per-row logsumexp + NLL mean
__global__ __launch_bounds__(256) void k_loss(const float* __restrict__ partial,
                                              const float* __restrict__ scores,
                                              const int* __restrict__ labels,
                                              float* __restrict__ out_loss) {
    int b = blockIdx.x, t = threadIdx.x;
    float acc = 0.f;
    for (int i = t; i < NBT; i += 256) acc += partial[(size_t)i * B_SZ + b];
    __shared__ float red[256];
    red[t] = acc;
    __syncthreads();
    for (int s = 128; s > 0; s >>= 1) {
        if (t < s) red[t] += red[t + s];
        __syncthreads();
    }
    if (t == 0) {
        int lab = labels[b];
        float val = scores[(size_t)b * N_SZ + lab] - logf(red[0]);
        atomicAdd(out_loss, -val * (1.0f / (float)B_SZ));
    }
}

extern "C" void kernel_launch(void* const* d_in, const int* in_sizes, int n_in,
                              void* d_out, int out_size, void* d_ws, size_t ws_size,
                              hipStream_t stream) {
    const int*   seeds    = (const int*)d_in[0];
    const int*   labels   = (const int*)d_in[1];
    const float* E        = (const float*)d_in[2];
    const float* W1       = (const float*)d_in[3];
    const float* W2       = (const float*)d_in[4];
    const float* q        = (const float*)d_in[5];
    const float* b_att    = (const float*)d_in[6];
    const float* out_bias = (const float*)d_in[7];
    const float* pe       = (const float*)d_in[8];

    float* scores = (float*)d_out;
    float* loss   = scores + (size_t)B_SZ * N_SZ;

    // ws layout: @2048 u_fr (64KB, fragment-ordered) | @67584 partial (1563*256*4 = 1.6MB)
    unsigned short* u_fr    = (unsigned short*)((char*)d_ws + 2048);
    float*          partial = (float*)((char*)d_ws + 67584);

    k_ub<<<B_SZ, 512, 0, stream>>>(seeds, E, pe, W1, W2, q, b_att, u_fr, loss);
    // k_gemm launched TWICE (idempotent) — measurement: dur_us ≈ tail + 2×G
    k_gemm<<<NBT, 256, 0, stream>>>(E, out_bias, u_fr, scores, partial);
    k_gemm<<<NBT, 256, 0, stream>>>(E, out_bias, u_fr, scores, partial);
    k_loss<<<B_SZ, 256, 0, stream>>>(partial, scores, labels, loss);
}